// Round 8
// baseline (63.301 us; speedup 1.0000x reference)
//
#include <hip/hip_runtime.h>

// Live dataflow of the reference (everything else is dead code — the
// reference pools the INPUT features x, never h):
//   x[i]      = emb_weight[global_idx[i]] + acts[i] @ pe_W + pe_b      [N,256]
//   pooled[g] = sum_{batch[i]==g} x[i]                                 [64,256]
//   z         = relu(pooled @ fc1_W + fc1_b)                           [64,512]
//   out       = log_softmax(z @ fc2_W + fc2_b)                         [64,978]
//
// Accounting model (R3-R7 all reconcile): dur_us ≈ 41 µs fixed harness
// poison-fill of the 256 MiB workspace (also evicts L3 every replay)
// + our kernels (~22 µs). This round: break pool_k's per-group dependence
// chain (idx-load -> gather -> add -> next idx-load) with a 16-row body
// using two independent register groups, so two groups' gathers overlap.

#define NNODES  100000
#define NGRAPHS 64
#define DIM     256
#define HID     512
#define NOUT    978
#define SUBS    8        // sub-blocks per graph; grid = 64*8 = 512 blocks
#define CHUNKS  32       // chunks per graph = SUBS * 4 waves

// ---------------------------------------------------------------------------
// Kernel 1: fused embed + pe-linear + segment-sum, atomic-free.
// Block b = (graph g = b/8, slice s = b%8). Range [lo,hi) via inline dual
// binary search on sorted batch (wave-uniform). Each of 4 waves sums a
// contiguous ~len/32 chunk; 16-row software-pipelined body with independent
// A/B register groups (16 outstanding 1KB gathers + decoupled metadata).
// pe term folded via (sum acts, count). LDS-reduce, one plain-store row.
// ---------------------------------------------------------------------------
__global__ __launch_bounds__(256) void pool_k(
    const int* __restrict__ gidx, const float* __restrict__ acts,
    const int* __restrict__ batch, const float* __restrict__ emb,
    const float* __restrict__ peW, const float* __restrict__ peb,
    float* __restrict__ partials)
{
    const int b    = blockIdx.x;
    const int g    = b >> 3;
    const int s    = b & 7;
    const int w    = threadIdx.x >> 6;
    const int lane = threadIdx.x & 63;

    // dual lower_bound: lo = first i with batch[i] >= g, hi = ... >= g+1.
    int l0 = 0, r0 = NNODES, l1 = 0, r1 = NNODES;
#pragma unroll
    for (int it = 0; it < 17; ++it) {
        if (l0 < r0) { const int m = (l0 + r0) >> 1; if (batch[m] <  g)     l0 = m + 1; else r0 = m; }
        if (l1 < r1) { const int m = (l1 + r1) >> 1; if (batch[m] <  g + 1) l1 = m + 1; else r1 = m; }
    }
    const int lo = l0, hi = l1;

    const int cw    = s * 4 + w;                  // 0..31 chunk id within graph
    const int chunk = (hi - lo + CHUNKS - 1) >> 5;
    int       i     = lo + cw * chunk;
    const int iend  = min(i + chunk, hi);

    const float4 w0 = ((const float4*)peW)[lane];          // pe_W row 0 slice
    const float4 w1 = ((const float4*)(peW + DIM))[lane];  // pe_W row 1 slice
    const float4 pb = ((const float4*)peb)[lane];          // pe_b slice

    float4 accA = make_float4(0.f, 0.f, 0.f, 0.f);
    float4 accB = make_float4(0.f, 0.f, 0.f, 0.f);
    float  axA = 0.f, ayA = 0.f, axB = 0.f, ayB = 0.f, cnt = 0.f;

#define EROW(P) (*(const float4*)(emb + ((size_t)(P) << 8) + lane * 4))
    // 16-row pipelined body: groups A (i..i+7) and B (i+8..i+15) are fully
    // independent register sets -> 16 gathers + 16 metadata loads in flight.
    for (; i + 16 <= iend; i += 16) {
        const int jA0 = gidx[i + 0], jA1 = gidx[i + 1], jA2 = gidx[i + 2], jA3 = gidx[i + 3];
        const int jA4 = gidx[i + 4], jA5 = gidx[i + 5], jA6 = gidx[i + 6], jA7 = gidx[i + 7];
        const int jB0 = gidx[i + 8], jB1 = gidx[i + 9], jB2 = gidx[i +10], jB3 = gidx[i +11];
        const int jB4 = gidx[i +12], jB5 = gidx[i +13], jB6 = gidx[i +14], jB7 = gidx[i +15];
        const float2 aA0 = ((const float2*)acts)[i + 0], aA1 = ((const float2*)acts)[i + 1];
        const float2 aA2 = ((const float2*)acts)[i + 2], aA3 = ((const float2*)acts)[i + 3];
        const float2 aA4 = ((const float2*)acts)[i + 4], aA5 = ((const float2*)acts)[i + 5];
        const float2 aA6 = ((const float2*)acts)[i + 6], aA7 = ((const float2*)acts)[i + 7];
        const float2 aB0 = ((const float2*)acts)[i + 8], aB1 = ((const float2*)acts)[i + 9];
        const float2 aB2 = ((const float2*)acts)[i +10], aB3 = ((const float2*)acts)[i +11];
        const float2 aB4 = ((const float2*)acts)[i +12], aB5 = ((const float2*)acts)[i +13];
        const float2 aB6 = ((const float2*)acts)[i +14], aB7 = ((const float2*)acts)[i +15];
        const float4 eA0 = EROW(jA0), eA1 = EROW(jA1), eA2 = EROW(jA2), eA3 = EROW(jA3);
        const float4 eA4 = EROW(jA4), eA5 = EROW(jA5), eA6 = EROW(jA6), eA7 = EROW(jA7);
        const float4 eB0 = EROW(jB0), eB1 = EROW(jB1), eB2 = EROW(jB2), eB3 = EROW(jB3);
        const float4 eB4 = EROW(jB4), eB5 = EROW(jB5), eB6 = EROW(jB6), eB7 = EROW(jB7);

        accA.x += ((eA0.x + eA1.x) + (eA2.x + eA3.x)) + ((eA4.x + eA5.x) + (eA6.x + eA7.x));
        accA.y += ((eA0.y + eA1.y) + (eA2.y + eA3.y)) + ((eA4.y + eA5.y) + (eA6.y + eA7.y));
        accA.z += ((eA0.z + eA1.z) + (eA2.z + eA3.z)) + ((eA4.z + eA5.z) + (eA6.z + eA7.z));
        accA.w += ((eA0.w + eA1.w) + (eA2.w + eA3.w)) + ((eA4.w + eA5.w) + (eA6.w + eA7.w));
        axA    += ((aA0.x + aA1.x) + (aA2.x + aA3.x)) + ((aA4.x + aA5.x) + (aA6.x + aA7.x));
        ayA    += ((aA0.y + aA1.y) + (aA2.y + aA3.y)) + ((aA4.y + aA5.y) + (aA6.y + aA7.y));

        accB.x += ((eB0.x + eB1.x) + (eB2.x + eB3.x)) + ((eB4.x + eB5.x) + (eB6.x + eB7.x));
        accB.y += ((eB0.y + eB1.y) + (eB2.y + eB3.y)) + ((eB4.y + eB5.y) + (eB6.y + eB7.y));
        accB.z += ((eB0.z + eB1.z) + (eB2.z + eB3.z)) + ((eB4.z + eB5.z) + (eB6.z + eB7.z));
        accB.w += ((eB0.w + eB1.w) + (eB2.w + eB3.w)) + ((eB4.w + eB5.w) + (eB6.w + eB7.w));
        axB    += ((aB0.x + aB1.x) + (aB2.x + aB3.x)) + ((aB4.x + aB5.x) + (aB6.x + aB7.x));
        ayB    += ((aB0.y + aB1.y) + (aB2.y + aB3.y)) + ((aB4.y + aB5.y) + (aB6.y + aB7.y));
        cnt    += 16.f;
    }
    for (; i + 8 <= iend; i += 8) {               // one 8-row group
        const int j0 = gidx[i + 0], j1 = gidx[i + 1], j2 = gidx[i + 2], j3 = gidx[i + 3];
        const int j4 = gidx[i + 4], j5 = gidx[i + 5], j6 = gidx[i + 6], j7 = gidx[i + 7];
        const float2 a0 = ((const float2*)acts)[i + 0], a1 = ((const float2*)acts)[i + 1];
        const float2 a2 = ((const float2*)acts)[i + 2], a3 = ((const float2*)acts)[i + 3];
        const float2 a4 = ((const float2*)acts)[i + 4], a5 = ((const float2*)acts)[i + 5];
        const float2 a6 = ((const float2*)acts)[i + 6], a7 = ((const float2*)acts)[i + 7];
        const float4 e0 = EROW(j0), e1 = EROW(j1), e2 = EROW(j2), e3 = EROW(j3);
        const float4 e4 = EROW(j4), e5 = EROW(j5), e6 = EROW(j6), e7 = EROW(j7);
        accA.x += ((e0.x + e1.x) + (e2.x + e3.x)) + ((e4.x + e5.x) + (e6.x + e7.x));
        accA.y += ((e0.y + e1.y) + (e2.y + e3.y)) + ((e4.y + e5.y) + (e6.y + e7.y));
        accA.z += ((e0.z + e1.z) + (e2.z + e3.z)) + ((e4.z + e5.z) + (e6.z + e7.z));
        accA.w += ((e0.w + e1.w) + (e2.w + e3.w)) + ((e4.w + e5.w) + (e6.w + e7.w));
        axA    += ((a0.x + a1.x) + (a2.x + a3.x)) + ((a4.x + a5.x) + (a6.x + a7.x));
        ayA    += ((a0.y + a1.y) + (a2.y + a3.y)) + ((a4.y + a5.y) + (a6.y + a7.y));
        cnt    += 8.f;
    }
    for (; i < iend; ++i) {                       // <=7 tail rows
        const int    j = gidx[i];
        const float2 a = ((const float2*)acts)[i];
        const float4 e = EROW(j);
        accA.x += e.x; accA.y += e.y; accA.z += e.z; accA.w += e.w;
        axA += a.x; ayA += a.y; cnt += 1.f;
    }
#undef EROW

    // merge groups + fold pe contribution: sum_i (acts_i @ pe_W + pe_b)
    const float ax = axA + axB, ay = ayA + ayB;
    float4 acc;
    acc.x = (accA.x + accB.x) + (ax * w0.x + ay * w1.x + cnt * pb.x);
    acc.y = (accA.y + accB.y) + (ax * w0.y + ay * w1.y + cnt * pb.y);
    acc.z = (accA.z + accB.z) + (ax * w0.z + ay * w1.z + cnt * pb.z);
    acc.w = (accA.w + accB.w) + (ax * w0.w + ay * w1.w + cnt * pb.w);

    // reduce the block's 4 waves in LDS; wave 0 writes the partials row
    __shared__ float4 red[4][64];
    red[w][lane] = acc;
    __syncthreads();
    if (w == 0) {
        const float4 r0_ = red[0][lane], r1_ = red[1][lane];
        const float4 r2_ = red[2][lane], r3_ = red[3][lane];
        float4 o;
        o.x = (r0_.x + r1_.x) + (r2_.x + r3_.x);
        o.y = (r0_.y + r1_.y) + (r2_.y + r3_.y);
        o.z = (r0_.z + r1_.z) + (r2_.z + r3_.z);
        o.w = (r0_.w + r1_.w) + (r2_.w + r3_.w);
        ((float4*)(partials + (size_t)b * DIM))[lane] = o;   // plain store
    }
}

// ---------------------------------------------------------------------------
// Kernel 2: z = relu(pooled @ fc1_W + fc1_b); pooled[g] = sum of the graph's
// SUBS partial rows (summed on the fly). Grid (4 col-tiles of 128, 64
// graphs), 128-thread blocks: 128 KB of W1 per block.
// ---------------------------------------------------------------------------
__global__ __launch_bounds__(128) void fc1_k(
    const float* __restrict__ partials, const float* __restrict__ W,
    const float* __restrict__ bias, float* __restrict__ z)
{
    __shared__ float xs[DIM];
    const int g = blockIdx.y;
    const int j = blockIdx.x * 128 + threadIdx.x;   // 0..511

    const float* pg = partials + (size_t)(g << 3) * DIM;
#pragma unroll
    for (int c = threadIdx.x; c < DIM; c += 128) {
        float v = 0.f;
#pragma unroll
        for (int s = 0; s < SUBS; ++s) v += pg[s * DIM + c];   // coalesced
        xs[c] = v;
    }
    __syncthreads();

    float acc = bias[j];
#pragma unroll 4
    for (int d = 0; d < DIM; d += 4) {
        const float4 x4 = *(const float4*)(xs + d);
        acc = fmaf(x4.x, W[(d + 0) * HID + j], acc);
        acc = fmaf(x4.y, W[(d + 1) * HID + j], acc);
        acc = fmaf(x4.z, W[(d + 2) * HID + j], acc);
        acc = fmaf(x4.w, W[(d + 3) * HID + j], acc);
    }
    z[g * HID + j] = fmaxf(acc, 0.f);
}

// ---------------------------------------------------------------------------
// Kernel 3a: logits = z @ fc2_W + fc2_b into d_out.  Grid (8 col-tiles of
// 128, 16 graph-quads), 128-thread blocks: 256 KB of W2 per block, each W
// column load feeds FOUR graphs' FMAs.
// ---------------------------------------------------------------------------
__global__ __launch_bounds__(128) void fc2_k(
    const float* __restrict__ z, const float* __restrict__ W,
    const float* __restrict__ bias, float* __restrict__ out)
{
    __shared__ float zs[4 * HID];
    const int g0 = blockIdx.y * 4;
    const int j = blockIdx.x * 128 + threadIdx.x;   // 0..1023
#pragma unroll
    for (int k = 0; k < 16; ++k) {
        const int idx = threadIdx.x + k * 128;      // 0..2047
        zs[idx] = z[g0 * HID + idx];                // rows g0..g0+3
    }
    __syncthreads();
    if (j >= NOUT) return;

    float acc0 = bias[j], acc1 = acc0, acc2 = acc0, acc3 = acc0;
#pragma unroll 2
    for (int d = 0; d < HID; d += 4) {
        const float4 za = *(const float4*)(zs + d);
        const float4 zb = *(const float4*)(zs + HID + d);
        const float4 zc = *(const float4*)(zs + 2 * HID + d);
        const float4 zd = *(const float4*)(zs + 3 * HID + d);
        const float wa = W[(d + 0) * NOUT + j];
        const float wb = W[(d + 1) * NOUT + j];
        const float wc = W[(d + 2) * NOUT + j];
        const float wd = W[(d + 3) * NOUT + j];
        acc0 = fmaf(za.x, wa, acc0); acc1 = fmaf(zb.x, wa, acc1);
        acc2 = fmaf(zc.x, wa, acc2); acc3 = fmaf(zd.x, wa, acc3);
        acc0 = fmaf(za.y, wb, acc0); acc1 = fmaf(zb.y, wb, acc1);
        acc2 = fmaf(zc.y, wb, acc2); acc3 = fmaf(zd.y, wb, acc3);
        acc0 = fmaf(za.z, wc, acc0); acc1 = fmaf(zb.z, wc, acc1);
        acc2 = fmaf(zc.z, wc, acc2); acc3 = fmaf(zd.z, wc, acc3);
        acc0 = fmaf(za.w, wd, acc0); acc1 = fmaf(zb.w, wd, acc1);
        acc2 = fmaf(zc.w, wd, acc2); acc3 = fmaf(zd.w, wd, acc3);
    }
    out[(size_t)(g0 + 0) * NOUT + j] = acc0;
    out[(size_t)(g0 + 1) * NOUT + j] = acc1;
    out[(size_t)(g0 + 2) * NOUT + j] = acc2;
    out[(size_t)(g0 + 3) * NOUT + j] = acc3;
}

// ---------------------------------------------------------------------------
// Kernel 3b: in-place row log-softmax.  One block (4 waves) per graph row.
// ---------------------------------------------------------------------------
__global__ __launch_bounds__(256) void lsm_k(float* __restrict__ out)
{
    __shared__ float red[8];
    const int g = blockIdx.x;
    float* row = out + (size_t)g * NOUT;
    const int tid  = threadIdx.x;
    const int wid  = tid >> 6;
    const int lane = tid & 63;

    float v[4];
    float m = -INFINITY;
#pragma unroll
    for (int k = 0; k < 4; ++k) {
        const int j = tid + k * 256;
        v[k] = (j < NOUT) ? row[j] : -INFINITY;
        m = fmaxf(m, v[k]);
    }
#pragma unroll
    for (int off = 32; off > 0; off >>= 1) m = fmaxf(m, __shfl_xor(m, off));
    if (lane == 0) red[wid] = m;
    __syncthreads();
    m = fmaxf(fmaxf(red[0], red[1]), fmaxf(red[2], red[3]));

    float s = 0.f;
#pragma unroll
    for (int k = 0; k < 4; ++k) {
        const int j = tid + k * 256;
        if (j < NOUT) s += expf(v[k] - m);
    }
#pragma unroll
    for (int off = 32; off > 0; off >>= 1) s += __shfl_xor(s, off);
    if (lane == 0) red[4 + wid] = s;
    __syncthreads();
    s = red[4] + red[5] + red[6] + red[7];

    const float lse = m + logf(s);
#pragma unroll
    for (int k = 0; k < 4; ++k) {
        const int j = tid + k * 256;
        if (j < NOUT) row[j] = v[k] - lse;
    }
}

// ---------------------------------------------------------------------------
extern "C" void kernel_launch(void* const* d_in, const int* in_sizes, int n_in,
                              void* d_out, int out_size, void* d_ws, size_t ws_size,
                              hipStream_t stream)
{
    // setup_inputs() dict order
    const int*   gidx  = (const int*)  d_in[0];   // global_idx  [N]
    const float* acts  = (const float*)d_in[1];   // acts        [N,2]
    const int*   batch = (const int*)  d_in[4];   // batch       [N] (sorted)
    const float* emb   = (const float*)d_in[5];   // emb_weight  [20000,256]
    const float* peW   = (const float*)d_in[6];   // pe_W        [2,256]
    const float* peb   = (const float*)d_in[7];   // pe_b        [256]
    const float* fc1W  = (const float*)d_in[19];  // fc1_W       [256,512]
    const float* fc1b  = (const float*)d_in[20];  // fc1_b       [512]
    const float* fc2W  = (const float*)d_in[21];  // fc2_W       [512,978]
    const float* fc2b  = (const float*)d_in[22];  // fc2_b       [978]
    // d_in[2,3,8..18] (edge_index, sign, cg_*, gat_*, bn_*, prelu) are dead
    // code w.r.t. the reference output (it pools x, not h).

    float* partials = (float*)d_ws;                      // 512*256 f32 = 512 KB
    float* z        = partials + NGRAPHS * SUBS * DIM;   // 64*512 f32 = 128 KB
    // No zeroing: partials/z/out are fully overwritten every call.

    pool_k<<<NGRAPHS * SUBS, 256, 0, stream>>>(gidx, acts, batch, emb, peW, peb, partials);
    fc1_k<<<dim3(4, NGRAPHS), 128, 0, stream>>>(partials, fc1W, fc1b, z);
    fc2_k<<<dim3(8, NGRAPHS / 4), 128, 0, stream>>>(z, fc2W, fc2b, (float*)d_out);
    lsm_k<<<NGRAPHS, 256, 0, stream>>>((float*)d_out);
}

// Round 9
// 61.993 us; speedup vs baseline: 1.0211x; 1.0211x over previous
//
#include <hip/hip_runtime.h>

// Live dataflow of the reference (everything else is dead code — the
// reference pools the INPUT features x, never h):
//   x[i]      = emb_weight[global_idx[i]] + acts[i] @ pe_W + pe_b      [N,256]
//   pooled[g] = sum_{batch[i]==g} x[i]                                 [64,256]
//   z         = relu(pooled @ fc1_W + fc1_b)                           [64,512]
//   out       = log_softmax(z @ fc2_W + fc2_b)                         [64,978]
//
// Accounting model (R3-R8 reconcile): dur_us ≈ 41 µs fixed harness poison-
// fill of the 256 MiB workspace (also evicts L3 every replay) + our kernels.
// R8 (deeper ILP) and R7 (2x TLP) were both null -> pool is near its gather
// throughput floor. This round removes the two remaining overheads:
// windowed binary search (17->11 iters, kills the per-block prologue
// bubble) and lean 8-deep body (VGPR ~76) + SUBS=16 for 4 blocks/CU.

#define NNODES  100000
#define NGRAPHS 64
#define DIM     256
#define HID     512
#define NOUT    978
#define SUBS    16       // sub-blocks per graph; grid = 64*16 = 1024 blocks
#define CHUNKS  64       // chunks per graph = SUBS * 4 waves

// Windowed lower_bound: first i with batch[i] >= v. batch is sorted counts
// of a uniform multinomial, so the answer lies near v*N/64 (sigma ~158);
// search a +-1024 window (11 iters) and fall back to a full 17-iter search
// if the verify fails (wave-uniform, never taken for valid inputs).
__device__ __forceinline__ int lower_bound_w(const int* __restrict__ batch, int v)
{
    const int c = (int)(((long long)v * NNODES) >> 6);
    int l = c - 1024; l = l < 0 ? 0 : l;
    int r = c + 1024; r = r > NNODES ? NNODES : r;
#pragma unroll
    for (int it = 0; it < 11; ++it) {
        if (l < r) { const int m = (l + r) >> 1; if (batch[m] < v) l = m + 1; else r = m; }
    }
    const bool ok = (l == 0      || batch[l - 1] <  v) &&
                    (l == NNODES || batch[l]     >= v);
    if (!ok) {                       // fallback: full-range search
        l = 0; r = NNODES;
#pragma unroll
        for (int it = 0; it < 17; ++it) {
            if (l < r) { const int m = (l + r) >> 1; if (batch[m] < v) l = m + 1; else r = m; }
        }
    }
    return l;
}

// ---------------------------------------------------------------------------
// Kernel 1: fused embed + pe-linear + segment-sum, atomic-free.
// Block b = (graph g = b/16, slice s = b%16). Each of 4 waves sums a
// contiguous ~len/64 chunk (groups of 8 -> 8 outstanding 1KB gathers);
// pe term folded via (sum acts, count). LDS-reduce, one plain-store row.
// 1024 blocks, lean VGPR budget -> 4 blocks/CU -> 16 waves/CU.
// ---------------------------------------------------------------------------
__global__ __launch_bounds__(256) void pool_k(
    const int* __restrict__ gidx, const float* __restrict__ acts,
    const int* __restrict__ batch, const float* __restrict__ emb,
    const float* __restrict__ peW, const float* __restrict__ peb,
    float* __restrict__ partials)
{
    const int b    = blockIdx.x;
    const int g    = b >> 4;
    const int s    = b & 15;
    const int w    = threadIdx.x >> 6;
    const int lane = threadIdx.x & 63;

    const int lo = lower_bound_w(batch, g);
    const int hi = lower_bound_w(batch, g + 1);

    const int cw    = s * 4 + w;                  // 0..63 chunk id within graph
    const int chunk = (hi - lo + CHUNKS - 1) >> 6;
    int       i     = lo + cw * chunk;
    const int iend  = min(i + chunk, hi);

    const float4 w0 = ((const float4*)peW)[lane];          // pe_W row 0 slice
    const float4 w1 = ((const float4*)(peW + DIM))[lane];  // pe_W row 1 slice
    const float4 pb = ((const float4*)peb)[lane];          // pe_b slice

    float4 acc = make_float4(0.f, 0.f, 0.f, 0.f);
    float  ax = 0.f, ay = 0.f, cnt = 0.f;

#define EROW(P) (*(const float4*)(emb + ((size_t)(P) << 8) + lane * 4))
    for (; i + 8 <= iend; i += 8) {
        // 8 independent index loads + 8 acts loads + 8 row gathers in flight
        const int j0 = gidx[i + 0], j1 = gidx[i + 1], j2 = gidx[i + 2], j3 = gidx[i + 3];
        const int j4 = gidx[i + 4], j5 = gidx[i + 5], j6 = gidx[i + 6], j7 = gidx[i + 7];
        const float2 a0 = ((const float2*)acts)[i + 0], a1 = ((const float2*)acts)[i + 1];
        const float2 a2 = ((const float2*)acts)[i + 2], a3 = ((const float2*)acts)[i + 3];
        const float2 a4 = ((const float2*)acts)[i + 4], a5 = ((const float2*)acts)[i + 5];
        const float2 a6 = ((const float2*)acts)[i + 6], a7 = ((const float2*)acts)[i + 7];
        const float4 e0 = EROW(j0), e1 = EROW(j1), e2 = EROW(j2), e3 = EROW(j3);
        const float4 e4 = EROW(j4), e5 = EROW(j5), e6 = EROW(j6), e7 = EROW(j7);

        acc.x += ((e0.x + e1.x) + (e2.x + e3.x)) + ((e4.x + e5.x) + (e6.x + e7.x));
        acc.y += ((e0.y + e1.y) + (e2.y + e3.y)) + ((e4.y + e5.y) + (e6.y + e7.y));
        acc.z += ((e0.z + e1.z) + (e2.z + e3.z)) + ((e4.z + e5.z) + (e6.z + e7.z));
        acc.w += ((e0.w + e1.w) + (e2.w + e3.w)) + ((e4.w + e5.w) + (e6.w + e7.w));
        ax    += ((a0.x + a1.x) + (a2.x + a3.x)) + ((a4.x + a5.x) + (a6.x + a7.x));
        ay    += ((a0.y + a1.y) + (a2.y + a3.y)) + ((a4.y + a5.y) + (a6.y + a7.y));
        cnt   += 8.f;
    }
    for (; i < iend; ++i) {                       // <=7 tail rows
        const int    j = gidx[i];
        const float2 a = ((const float2*)acts)[i];
        const float4 e = EROW(j);
        acc.x += e.x; acc.y += e.y; acc.z += e.z; acc.w += e.w;
        ax += a.x; ay += a.y; cnt += 1.f;
    }
#undef EROW

    // fold pe contribution: sum_i (acts_i @ pe_W + pe_b)
    acc.x += ax * w0.x + ay * w1.x + cnt * pb.x;
    acc.y += ax * w0.y + ay * w1.y + cnt * pb.y;
    acc.z += ax * w0.z + ay * w1.z + cnt * pb.z;
    acc.w += ax * w0.w + ay * w1.w + cnt * pb.w;

    // reduce the block's 4 waves in LDS; wave 0 writes the partials row
    __shared__ float4 red[4][64];
    red[w][lane] = acc;
    __syncthreads();
    if (w == 0) {
        const float4 r0_ = red[0][lane], r1_ = red[1][lane];
        const float4 r2_ = red[2][lane], r3_ = red[3][lane];
        float4 o;
        o.x = (r0_.x + r1_.x) + (r2_.x + r3_.x);
        o.y = (r0_.y + r1_.y) + (r2_.y + r3_.y);
        o.z = (r0_.z + r1_.z) + (r2_.z + r3_.z);
        o.w = (r0_.w + r1_.w) + (r2_.w + r3_.w);
        ((float4*)(partials + (size_t)b * DIM))[lane] = o;   // plain store
    }
}

// ---------------------------------------------------------------------------
// Kernel 2: z = relu(pooled @ fc1_W + fc1_b); pooled[g] = sum of the graph's
// SUBS partial rows (summed on the fly). Grid (4 col-tiles of 128, 64
// graphs), 128-thread blocks: 128 KB of W1 per block.
// ---------------------------------------------------------------------------
__global__ __launch_bounds__(128) void fc1_k(
    const float* __restrict__ partials, const float* __restrict__ W,
    const float* __restrict__ bias, float* __restrict__ z)
{
    __shared__ float xs[DIM];
    const int g = blockIdx.y;
    const int j = blockIdx.x * 128 + threadIdx.x;   // 0..511

    const float* pg = partials + (size_t)(g << 4) * DIM;
#pragma unroll
    for (int c = threadIdx.x; c < DIM; c += 128) {
        float v = 0.f;
#pragma unroll
        for (int s = 0; s < SUBS; ++s) v += pg[s * DIM + c];   // coalesced
        xs[c] = v;
    }
    __syncthreads();

    float acc = bias[j];
#pragma unroll 4
    for (int d = 0; d < DIM; d += 4) {
        const float4 x4 = *(const float4*)(xs + d);
        acc = fmaf(x4.x, W[(d + 0) * HID + j], acc);
        acc = fmaf(x4.y, W[(d + 1) * HID + j], acc);
        acc = fmaf(x4.z, W[(d + 2) * HID + j], acc);
        acc = fmaf(x4.w, W[(d + 3) * HID + j], acc);
    }
    z[g * HID + j] = fmaxf(acc, 0.f);
}

// ---------------------------------------------------------------------------
// Kernel 3a: logits = z @ fc2_W + fc2_b into d_out.  Grid (8 col-tiles of
// 128, 16 graph-quads), 128-thread blocks: 256 KB of W2 per block, each W
// column load feeds FOUR graphs' FMAs.
// ---------------------------------------------------------------------------
__global__ __launch_bounds__(128) void fc2_k(
    const float* __restrict__ z, const float* __restrict__ W,
    const float* __restrict__ bias, float* __restrict__ out)
{
    __shared__ float zs[4 * HID];
    const int g0 = blockIdx.y * 4;
    const int j = blockIdx.x * 128 + threadIdx.x;   // 0..1023
#pragma unroll
    for (int k = 0; k < 16; ++k) {
        const int idx = threadIdx.x + k * 128;      // 0..2047
        zs[idx] = z[g0 * HID + idx];                // rows g0..g0+3
    }
    __syncthreads();
    if (j >= NOUT) return;

    float acc0 = bias[j], acc1 = acc0, acc2 = acc0, acc3 = acc0;
#pragma unroll 2
    for (int d = 0; d < HID; d += 4) {
        const float4 za = *(const float4*)(zs + d);
        const float4 zb = *(const float4*)(zs + HID + d);
        const float4 zc = *(const float4*)(zs + 2 * HID + d);
        const float4 zd = *(const float4*)(zs + 3 * HID + d);
        const float wa = W[(d + 0) * NOUT + j];
        const float wb = W[(d + 1) * NOUT + j];
        const float wc = W[(d + 2) * NOUT + j];
        const float wd = W[(d + 3) * NOUT + j];
        acc0 = fmaf(za.x, wa, acc0); acc1 = fmaf(zb.x, wa, acc1);
        acc2 = fmaf(zc.x, wa, acc2); acc3 = fmaf(zd.x, wa, acc3);
        acc0 = fmaf(za.y, wb, acc0); acc1 = fmaf(zb.y, wb, acc1);
        acc2 = fmaf(zc.y, wb, acc2); acc3 = fmaf(zd.y, wb, acc3);
        acc0 = fmaf(za.z, wc, acc0); acc1 = fmaf(zb.z, wc, acc1);
        acc2 = fmaf(zc.z, wc, acc2); acc3 = fmaf(zd.z, wc, acc3);
        acc0 = fmaf(za.w, wd, acc0); acc1 = fmaf(zb.w, wd, acc1);
        acc2 = fmaf(zc.w, wd, acc2); acc3 = fmaf(zd.w, wd, acc3);
    }
    out[(size_t)(g0 + 0) * NOUT + j] = acc0;
    out[(size_t)(g0 + 1) * NOUT + j] = acc1;
    out[(size_t)(g0 + 2) * NOUT + j] = acc2;
    out[(size_t)(g0 + 3) * NOUT + j] = acc3;
}

// ---------------------------------------------------------------------------
// Kernel 3b: in-place row log-softmax.  One block (4 waves) per graph row.
// ---------------------------------------------------------------------------
__global__ __launch_bounds__(256) void lsm_k(float* __restrict__ out)
{
    __shared__ float red[8];
    const int g = blockIdx.x;
    float* row = out + (size_t)g * NOUT;
    const int tid  = threadIdx.x;
    const int wid  = tid >> 6;
    const int lane = tid & 63;

    float v[4];
    float m = -INFINITY;
#pragma unroll
    for (int k = 0; k < 4; ++k) {
        const int j = tid + k * 256;
        v[k] = (j < NOUT) ? row[j] : -INFINITY;
        m = fmaxf(m, v[k]);
    }
#pragma unroll
    for (int off = 32; off > 0; off >>= 1) m = fmaxf(m, __shfl_xor(m, off));
    if (lane == 0) red[wid] = m;
    __syncthreads();
    m = fmaxf(fmaxf(red[0], red[1]), fmaxf(red[2], red[3]));

    float s = 0.f;
#pragma unroll
    for (int k = 0; k < 4; ++k) {
        const int j = tid + k * 256;
        if (j < NOUT) s += expf(v[k] - m);
    }
#pragma unroll
    for (int off = 32; off > 0; off >>= 1) s += __shfl_xor(s, off);
    if (lane == 0) red[4 + wid] = s;
    __syncthreads();
    s = red[4] + red[5] + red[6] + red[7];

    const float lse = m + logf(s);
#pragma unroll
    for (int k = 0; k < 4; ++k) {
        const int j = tid + k * 256;
        if (j < NOUT) row[j] = v[k] - lse;
    }
}

// ---------------------------------------------------------------------------
extern "C" void kernel_launch(void* const* d_in, const int* in_sizes, int n_in,
                              void* d_out, int out_size, void* d_ws, size_t ws_size,
                              hipStream_t stream)
{
    // setup_inputs() dict order
    const int*   gidx  = (const int*)  d_in[0];   // global_idx  [N]
    const float* acts  = (const float*)d_in[1];   // acts        [N,2]
    const int*   batch = (const int*)  d_in[4];   // batch       [N] (sorted)
    const float* emb   = (const float*)d_in[5];   // emb_weight  [20000,256]
    const float* peW   = (const float*)d_in[6];   // pe_W        [2,256]
    const float* peb   = (const float*)d_in[7];   // pe_b        [256]
    const float* fc1W  = (const float*)d_in[19];  // fc1_W       [256,512]
    const float* fc1b  = (const float*)d_in[20];  // fc1_b       [512]
    const float* fc2W  = (const float*)d_in[21];  // fc2_W       [512,978]
    const float* fc2b  = (const float*)d_in[22];  // fc2_b       [978]
    // d_in[2,3,8..18] (edge_index, sign, cg_*, gat_*, bn_*, prelu) are dead
    // code w.r.t. the reference output (it pools x, not h).

    float* partials = (float*)d_ws;                      // 1024*256 f32 = 1 MB
    float* z        = partials + NGRAPHS * SUBS * DIM;   // 64*512 f32 = 128 KB
    // No zeroing: partials/z/out are fully overwritten every call.

    pool_k<<<NGRAPHS * SUBS, 256, 0, stream>>>(gidx, acts, batch, emb, peW, peb, partials);
    fc1_k<<<dim3(4, NGRAPHS), 128, 0, stream>>>(partials, fc1W, fc1b, z);
    fc2_k<<<dim3(8, NGRAPHS / 4), 128, 0, stream>>>(z, fc2W, fc2b, (float*)d_out);
    lsm_k<<<NGRAPHS, 256, 0, stream>>>((float*)d_out);
}